// Round 5
// baseline (390.800 us; speedup 1.0000x reference)
//
#include <hip/hip_runtime.h>
#include <hip/hip_bf16.h>

#define B_ 2
#define H_ 16
#define S_ 2048
#define D_ 64
#define BUFSTR 72                 // shorts per row of chunk buf (144B, 16B-aligned)
#define BUFSZ (16 * BUFSTR)       // shorts per wave chunk buf

typedef float f32x4 __attribute__((ext_vector_type(4)));
typedef short s16x8 __attribute__((ext_vector_type(8)));

__device__ __forceinline__ short f2bf(float f) {
  unsigned u = __float_as_uint(f);
  u += 0x7FFFu + ((u >> 16) & 1u);   // RTNE (finite inputs)
  return (short)(u >> 16);
}
__device__ __forceinline__ float bf2f(short s) {
  return __uint_as_float(((unsigned)(unsigned short)s) << 16);
}

// ---------------- prep: f32 -> bf16 (Q, K) ----------------
__global__ __launch_bounds__(256) void prep_qk(const float* __restrict__ q,
                                               const float* __restrict__ k,
                                               short* __restrict__ qbf,
                                               short* __restrict__ kbf) {
  size_t i = ((size_t)blockIdx.x * 256 + threadIdx.x) * 8;
  const f32x4* qa = (const f32x4*)(q + i);
  const f32x4* ka = (const f32x4*)(k + i);
  f32x4 a0 = __builtin_nontemporal_load(qa);
  f32x4 a1 = __builtin_nontemporal_load(qa + 1);
  f32x4 b0 = __builtin_nontemporal_load(ka);
  f32x4 b1 = __builtin_nontemporal_load(ka + 1);
  s16x8 oq, ok;
  #pragma unroll
  for (int e = 0; e < 4; ++e) {
    oq[e] = f2bf(a0[e]); oq[4 + e] = f2bf(a1[e]);
    ok[e] = f2bf(b0[e]); ok[4 + e] = f2bf(b1[e]);
  }
  *(s16x8*)(qbf + i) = oq;
  *(s16x8*)(kbf + i) = ok;
}

// ---------------- prep: V -> bf16 transposed Vt[bh][d][j] ----------------
__global__ __launch_bounds__(256) void prep_v(const float* __restrict__ v,
                                              short* __restrict__ vt) {
  __shared__ float tile[64][65];
  const int tid = threadIdx.x;
  const int j0 = blockIdx.x * 64;
  const int bh = blockIdx.y;
  const float* vh = v + (size_t)bh * S_ * D_;
  #pragma unroll
  for (int it = 0; it < 16; ++it) {
    int idx = it * 256 + tid;
    int row = idx >> 6, col = idx & 63;
    tile[row][col] = __builtin_nontemporal_load(&vh[(size_t)(j0 + row) * D_ + col]);
  }
  __syncthreads();
  short* vth = vt + (size_t)bh * D_ * S_;
  #pragma unroll
  for (int it = 0; it < 16; ++it) {
    int idx = it * 256 + tid;
    int d = idx >> 6, jj = idx & 63;
    vth[(size_t)d * S_ + j0 + jj] = f2bf(tile[jj][d]);
  }
}

// ---------------- fused single-pass kernel ----------------
// Per block: 16 q-rows. 8 waves each own 4 chunks of 64 j (interleaved).
// Per chunk: QK MFMA -> softcap -> register stash + wave-private LDS
// transpose -> PV MFMA. One barrier pair at the end for rowsum + PV reduce.
template <bool PRE>
__global__ __launch_bounds__(512, 4) void attend_fused(
    const float* __restrict__ q, const float* __restrict__ k,
    const float* __restrict__ v, const int* __restrict__ mask,
    const short* __restrict__ qbf, const short* __restrict__ kbf,
    const short* __restrict__ vt,
    float* __restrict__ out, float* __restrict__ attn) {
  // pvred (32KB) is reused: during phase 1 its first 18.4KB serve as the
  // 8 wave-private chunk-transpose buffers (union is safe: all cross-type
  // accesses are separated by __syncthreads).
  __shared__ float pvred[8][16][64];
  __shared__ float ls_rs[8][16];
  __shared__ float ls_rinv[16];

  const int tid  = threadIdx.x;
  const int wv   = tid >> 6;
  const int lane = tid & 63;
  const int lg   = lane >> 4;
  const int li   = lane & 15;

  const int q0 = blockIdx.x * 16;
  const int bh = blockIdx.y;
  const int b  = bh >> 4;
  const int* mrow = mask + (size_t)b * S_;

  short* myb = (short*)pvred + wv * BUFSZ;

  // Q A-fragment: lane holds Q[q0+li][ks*32 + lg*8 + e]
  s16x8 qf0, qf1;
  if constexpr (PRE) {
    const short* qr = qbf + ((size_t)bh * S_ + q0 + li) * D_ + lg * 8;
    qf0 = *(const s16x8*)qr;
    qf1 = *(const s16x8*)(qr + 32);
  } else {
    const float* qr = q + ((size_t)bh * S_ + q0 + li) * D_ + lg * 8;
    #pragma unroll
    for (int e = 0; e < 8; ++e) { qf0[e] = f2bf(qr[e]); qf1[e] = f2bf(qr[32 + e]); }
  }

  float rs[4] = {0.f, 0.f, 0.f, 0.f};
  f32x4 pvacc[4];
  #pragma unroll
  for (int m = 0; m < 4; ++m) pvacc[m] = (f32x4){0.f, 0.f, 0.f, 0.f};
  unsigned st[4][4][2];   // [chunk][n][rr] packed bf16 pairs (rows r=2rr,2rr+1)

  #pragma unroll
  for (int c = 0; c < 4; ++c) {
    const int jc = c * 512 + wv * 64;

    // ---- QK^T for this 64-j chunk ----
    f32x4 acc[4];
    #pragma unroll
    for (int n = 0; n < 4; ++n) acc[n] = (f32x4){0.f, 0.f, 0.f, 0.f};
    #pragma unroll
    for (int n = 0; n < 4; ++n) {
      if constexpr (PRE) {
        const short* kr = kbf + ((size_t)bh * S_ + jc + n * 16 + li) * D_ + lg * 8;
        acc[n] = __builtin_amdgcn_mfma_f32_16x16x32_bf16(qf0, *(const s16x8*)kr, acc[n], 0, 0, 0);
        acc[n] = __builtin_amdgcn_mfma_f32_16x16x32_bf16(qf1, *(const s16x8*)(kr + 32), acc[n], 0, 0, 0);
      } else {
        const float* kr = k + ((size_t)bh * S_ + jc + n * 16 + li) * D_ + lg * 8;
        s16x8 k0, k1;
        #pragma unroll
        for (int e = 0; e < 8; ++e) { k0[e] = f2bf(kr[e]); k1[e] = f2bf(kr[32 + e]); }
        acc[n] = __builtin_amdgcn_mfma_f32_16x16x32_bf16(qf0, k0, acc[n], 0, 0, 0);
        acc[n] = __builtin_amdgcn_mfma_f32_16x16x32_bf16(qf1, k1, acc[n], 0, 0, 0);
      }
    }

    // ---- softcap + mask + stash + LDS transpose write ----
    #pragma unroll
    for (int n = 0; n < 4; ++n) {
      const int j = jc + n * 16 + li;
      const bool keep = mrow[j] != 0;
      unsigned pk0 = 0, pk1 = 0;
      #pragma unroll
      for (int r = 0; r < 4; ++r) {
        float s = acc[n][r] * 0.125f;
        // p = exp(50*tanh(s/50) - 50) = exp(-100/(e^{2s/50}+1))
        float t = exp2f(s * 0.057707802f);
        float p = exp2f(-144.269504f * __builtin_amdgcn_rcpf(t + 1.f));
        p = keep ? p : 0.f;
        rs[r] += p;
        unsigned pb = (unsigned)(unsigned short)f2bf(p);
        if (r == 0) pk0 = pb;
        else if (r == 1) pk0 |= pb << 16;
        else if (r == 2) pk1 = pb;
        else pk1 |= pb << 16;
        myb[(lg * 4 + r) * BUFSTR + n * 16 + li] = (short)pb;
      }
      st[c][n][0] = pk0;
      st[c][n][1] = pk1;
    }

    // ---- PV for this chunk (wave-private transpose read, no barrier) ----
    #pragma unroll
    for (int ks = 0; ks < 2; ++ks) {
      s16x8 pa = *(const s16x8*)&myb[li * BUFSTR + ks * 32 + lg * 8];
      #pragma unroll
      for (int m = 0; m < 4; ++m) {
        s16x8 vb;
        if constexpr (PRE) {
          vb = *(const s16x8*)(vt + ((size_t)bh * D_ + m * 16 + li) * S_ + jc + ks * 32 + lg * 8);
        } else {
          const float* vp = v + (size_t)bh * S_ * D_ + (size_t)(jc + ks * 32 + lg * 8) * D_ + m * 16 + li;
          #pragma unroll
          for (int e = 0; e < 8; ++e) vb[e] = f2bf(vp[(size_t)e * D_]);
        }
        pvacc[m] = __builtin_amdgcn_mfma_f32_16x16x32_bf16(pa, vb, pvacc[m], 0, 0, 0);
      }
    }
  }

  // ---- row sums: reduce 16 lanes per lg group, stage per-wave ----
  #pragma unroll
  for (int r = 0; r < 4; ++r) {
    #pragma unroll
    for (int m = 1; m < 16; m <<= 1) rs[r] += __shfl_xor(rs[r], m, 64);
  }
  if (li == 0) {
    #pragma unroll
    for (int r = 0; r < 4; ++r) ls_rs[wv][lg * 4 + r] = rs[r];
  }
  __syncthreads();   // chunk bufs dead; ls_rs ready

  if (tid < 16) {
    float ssum = 0.f;
    #pragma unroll
    for (int w = 0; w < 8; ++w) ssum += ls_rs[w][tid];
    ls_rinv[tid] = (ssum > 0.f) ? 1.f / ssum : 0.f;
  }
  // PV partials into pvred (overlaps old chunk bufs — safe after barrier)
  #pragma unroll
  for (int m = 0; m < 4; ++m)
    #pragma unroll
    for (int r = 0; r < 4; ++r)
      pvred[wv][lg * 4 + r][m * 16 + li] = pvacc[m][r];
  __syncthreads();   // pvred + ls_rinv ready

  // ---- out = (sum_w PV_w) * rinv : 1024 outputs, 2 per thread ----
  #pragma unroll
  for (int h = 0; h < 2; ++h) {
    const int idx = h * 512 + tid;
    const int qq = idx >> 6, d = idx & 63;
    float ssum = 0.f;
    #pragma unroll
    for (int w = 0; w < 8; ++w) ssum += pvred[w][qq][d];
    out[((size_t)bh * S_ + q0 + qq) * D_ + d] = ssum * ls_rinv[qq];
  }

  // ---- attn writes from register stash (all 8 waves, NT stores) ----
  float rinv4[4];
  #pragma unroll
  for (int r = 0; r < 4; ++r) rinv4[r] = ls_rinv[lg * 4 + r];

  float* abase = attn + ((size_t)bh * S_ + q0 + lg * 4) * S_;
  #pragma unroll
  for (int c = 0; c < 4; ++c) {
    const int jc = c * 512 + wv * 64;
    #pragma unroll
    for (int n = 0; n < 4; ++n) {
      const int j = jc + n * 16 + li;
      #pragma unroll
      for (int rr = 0; rr < 2; ++rr) {
        unsigned pk = st[c][n][rr];
        float p0 = bf2f((short)(pk & 0xFFFFu)) * rinv4[2 * rr];
        float p1 = bf2f((short)(pk >> 16)) * rinv4[2 * rr + 1];
        __builtin_nontemporal_store(p0, abase + (size_t)(2 * rr) * S_ + j);
        __builtin_nontemporal_store(p1, abase + (size_t)(2 * rr + 1) * S_ + j);
      }
    }
  }
}

extern "C" void kernel_launch(void* const* d_in, const int* in_sizes, int n_in,
                              void* d_out, int out_size, void* d_ws, size_t ws_size,
                              hipStream_t stream) {
  const float* q = (const float*)d_in[0];
  const float* k = (const float*)d_in[1];
  const float* v = (const float*)d_in[2];
  const int* mask = (const int*)d_in[3];

  float* out  = (float*)d_out;
  const size_t nel = (size_t)B_ * H_ * S_ * D_;
  float* attn = out + nel;

  dim3 grid(S_ / 16, B_ * H_);
  const size_t need = nel * 2 * 3;   // Qbf + Kbf + Vt, bf16

  if (ws_size >= need) {
    short* qbf = (short*)d_ws;
    short* kbf = qbf + nel;
    short* vtp = kbf + nel;
    prep_qk<<<(int)(nel / (256 * 8)), 256, 0, stream>>>(q, k, qbf, kbf);
    prep_v<<<dim3(S_ / 64, B_ * H_), 256, 0, stream>>>(v, vtp);
    attend_fused<true><<<grid, 512, 0, stream>>>(q, k, v, mask, qbf, kbf, vtp, out, attn);
  } else {
    attend_fused<false><<<grid, 512, 0, stream>>>(q, k, v, mask, nullptr, nullptr, nullptr, out, attn);
  }
}